// Round 1
// baseline (511.733 us; speedup 1.0000x reference)
//
#include <hip/hip_runtime.h>

using u16 = unsigned short;
using u32 = unsigned int;

typedef __attribute__((ext_vector_type(8))) __bf16 bf16x8;
typedef __attribute__((ext_vector_type(4))) float f32x4;

__device__ __forceinline__ u16 f2bf(float f) {
  u32 u = __builtin_bit_cast(u32, f);
  u = (u + 0x7fffu + ((u >> 16) & 1u)) >> 16;
  return (u16)u;
}
__device__ __forceinline__ float bf2f(u16 h) {
  u32 u = ((u32)h) << 16;
  return __builtin_bit_cast(float, u);
}

// ---------------------------------------------------------------- cvt fp32->bf16
__global__ void cvt_kernel(const float* __restrict__ in, u16* __restrict__ out, int n4) {
  int idx = blockIdx.x * blockDim.x + threadIdx.x;
  int stride = gridDim.x * blockDim.x;
  for (int i = idx; i < n4; i += stride) {
    float4 f = ((const float4*)in)[i];
    ushort4 o;
    o.x = f2bf(f.x); o.y = f2bf(f.y); o.z = f2bf(f.z); o.w = f2bf(f.w);
    ((ushort4*)out)[i] = o;
  }
}

// ---------------------------------------------------------------- GEMM C = A * B^T
// A: [M][K] bf16 row-major, B: [N][K] bf16 row-major, C: [M][N]
// 128x128 tile, BK=32, 256 threads = 4 waves (2x2 of 64x64)
template <int OUT_BF16>
__global__ __launch_bounds__(256) void gemm_bt(const u16* __restrict__ A,
                                               const u16* __restrict__ B,
                                               void* __restrict__ Cv,
                                               int M, int N, int K) {
  __shared__ alignas(16) u16 As[128 * 32];
  __shared__ alignas(16) u16 Bs[128 * 32];
  const int tid = threadIdx.x;
  const int w = tid >> 6, lane = tid & 63;
  const int g = lane >> 4, lo = lane & 15;
  const int bm = blockIdx.y * 128, bn = blockIdx.x * 128;
  const int wm = (w >> 1) * 64, wn = (w & 1) * 64;
  const int srow = lane >> 2;        // 0..15
  const int skp = (lane & 3) * 8;    // k offset of this lane's 16B
  f32x4 acc[4][4] = {};

  for (int k0 = 0; k0 < K; k0 += 32) {
#pragma unroll
    for (int c2 = 0; c2 < 2; ++c2) {
      const int c = 2 * w + c2;
      const int row = c * 16 + srow;
      const u16* ga = A + (size_t)(bm + row) * K + k0 + skp;
      const u16* gb = B + (size_t)(bn + row) * K + k0 + skp;
      __builtin_amdgcn_global_load_lds((const __attribute__((address_space(1))) void*)ga,
                                       (__attribute__((address_space(3))) void*)(As + c * 512),
                                       16, 0, 0);
      __builtin_amdgcn_global_load_lds((const __attribute__((address_space(1))) void*)gb,
                                       (__attribute__((address_space(3))) void*)(Bs + c * 512),
                                       16, 0, 0);
    }
    __syncthreads();
    bf16x8 af[4], bfr[4];
#pragma unroll
    for (int i = 0; i < 4; ++i) {
      af[i] = *(const bf16x8*)(As + (wm + i * 16 + lo) * 32 + g * 8);
      bfr[i] = *(const bf16x8*)(Bs + (wn + i * 16 + lo) * 32 + g * 8);
    }
#pragma unroll
    for (int i = 0; i < 4; ++i)
#pragma unroll
      for (int j = 0; j < 4; ++j)
        acc[i][j] = __builtin_amdgcn_mfma_f32_16x16x32_bf16(af[i], bfr[j], acc[i][j], 0, 0, 0);
    __syncthreads();
  }

#pragma unroll
  for (int i = 0; i < 4; ++i) {
#pragma unroll
    for (int r = 0; r < 4; ++r) {
      const int row = bm + wm + i * 16 + g * 4 + r;
#pragma unroll
      for (int j = 0; j < 4; ++j) {
        const int col = bn + wn + j * 16 + lo;
        float v = acc[i][j][r];
        if (OUT_BF16)
          ((u16*)Cv)[(size_t)row * N + col] = f2bf(v);
        else
          ((float*)Cv)[(size_t)row * N + col] = v;
      }
    }
  }
}

// ---------------------------------------------------------------- RoPE + layout
// qkv: [4096][6144] bf16 (row = b*2048+l; col = part*2048 + h*64 + d)
// Q,K out: [64 bh][2048][64]; VT out: [64 bh][64 d][2048 l]
__global__ __launch_bounds__(256) void rope_kernel(const u16* __restrict__ qkv,
                                                   u16* __restrict__ Q,
                                                   u16* __restrict__ Ko,
                                                   u16* __restrict__ VT) {
  const int bh = blockIdx.x;  // 0..63
  const int lt = blockIdx.y;  // 0..31
  const int b = bh >> 5, h = bh & 31;
  const int tid = threadIdx.x;
  const int l0 = lt * 64;

  const int i = tid & 31;  // freq index (fixed per thread)
  const float invf = exp2f(-(float)i * 0.28125f);  // 512^(-i/32)
#pragma unroll
  for (int it = 0; it < 8; ++it) {
    const int l = (tid >> 5) + it * 8;  // 0..63
    const int m = b * 2048 + l0 + l;
    float s, c;
    __sincosf((float)(l0 + l) * invf, &s, &c);
    const int base = m * 6144 + h * 64 + i;
    float qlo = bf2f(qkv[base]), qhi = bf2f(qkv[base + 32]);
    float klo = bf2f(qkv[base + 2048]), khi = bf2f(qkv[base + 2048 + 32]);
    const int ob = (bh * 2048 + l0 + l) * 64 + i;
    Q[ob] = f2bf(qlo * c - qhi * s);
    Q[ob + 32] = f2bf(qhi * c + qlo * s);
    Ko[ob] = f2bf(klo * c - khi * s);
    Ko[ob + 32] = f2bf(khi * c + klo * s);
  }

  // V transpose via LDS: read [l][d] tile, write [d][l]
  __shared__ alignas(16) u16 vs[64][72];
#pragma unroll
  for (int it = 0; it < 2; ++it) {
    const int c = tid * 2 + it;  // 0..511 chunks of 8 elems
    const int l = c >> 3, off = (c & 7) * 8;
    const int m = b * 2048 + l0 + l;
    *(uint4*)&vs[l][off] = *(const uint4*)&qkv[m * 6144 + 4096 + h * 64 + off];
  }
  __syncthreads();
#pragma unroll
  for (int it = 0; it < 2; ++it) {
    const int c = tid * 2 + it;
    const int d = c >> 3, lc = (c & 7) * 8;
    u32 w0 = (u32)vs[lc + 0][d] | ((u32)vs[lc + 1][d] << 16);
    u32 w1 = (u32)vs[lc + 2][d] | ((u32)vs[lc + 3][d] << 16);
    u32 w2 = (u32)vs[lc + 4][d] | ((u32)vs[lc + 5][d] << 16);
    u32 w3 = (u32)vs[lc + 6][d] | ((u32)vs[lc + 7][d] << 16);
    uint4 pk; pk.x = w0; pk.y = w1; pk.z = w2; pk.w = w3;
    *(uint4*)&VT[(size_t)(bh * 64 + d) * 2048 + l0 + lc] = pk;
  }
}

// ---------------------------------------------------------------- flash attention (causal)
// Q,K: [64][2048][64] bf16; VT: [64][64][2048] bf16; O: [4096][2048] ([b][l][h*64+d])
__global__ __launch_bounds__(256) void flash_kernel(const u16* __restrict__ Q,
                                                    const u16* __restrict__ K,
                                                    const u16* __restrict__ V,
                                                    u16* __restrict__ O) {
  __shared__ alignas(16) u16 Ks[64][72];
  __shared__ alignas(16) u16 Vs[64][72];
  __shared__ alignas(16) u16 Ps[4][32][72];
  const int qt = 15 - blockIdx.x;  // heavy tiles first
  const int bh = blockIdx.y;
  const int b = bh >> 5, h = bh & 31;
  const int tid = threadIdx.x;
  const int w = tid >> 6, lane = tid & 63;
  const int g = lane >> 4, lo = lane & 15;
  const int qbase = qt * 128 + w * 32;

  // Q fragments (B-operand of swapped QK^T): qf[qj][ks]
  bf16x8 qf[2][2];
#pragma unroll
  for (int qj = 0; qj < 2; ++qj)
#pragma unroll
    for (int ks = 0; ks < 2; ++ks)
      qf[qj][ks] = *(const bf16x8*)(Q + (size_t)(bh * 2048 + qbase + qj * 16 + lo) * 64 + ks * 32 + g * 8);

  float mo[2] = {-1e30f, -1e30f};
  float ls[2] = {0.f, 0.f};
  f32x4 oacc[2][4] = {};

  const int ntile = 2 * qt + 2;
  for (int t = 0; t < ntile; ++t) {
    const int kv0 = t * 64;
    {  // stage K tile [64 kv][64 d] and V^T tile [64 d][64 kv]
      const int row = tid >> 2, ch = tid & 3;
      const uint4* gk = (const uint4*)(K + (size_t)(bh * 2048 + kv0 + row) * 64 + ch * 16);
      uint4 ka = gk[0], kb = gk[1];
      const uint4* gv = (const uint4*)(V + (size_t)(bh * 64 + row) * 2048 + kv0 + ch * 16);
      uint4 va = gv[0], vb4 = gv[1];
      *(uint4*)&Ks[row][ch * 16] = ka;
      *(uint4*)&Ks[row][ch * 16 + 8] = kb;
      *(uint4*)&Vs[row][ch * 16] = va;
      *(uint4*)&Vs[row][ch * 16 + 8] = vb4;
    }
    __syncthreads();

    // S^T[kv][q] = sum_d K[kv][d] Q[q][d]
    f32x4 st[4][2] = {};
#pragma unroll
    for (int kvi = 0; kvi < 4; ++kvi)
#pragma unroll
      for (int ks = 0; ks < 2; ++ks) {
        bf16x8 kf = *(const bf16x8*)&Ks[kvi * 16 + lo][ks * 32 + g * 8];
#pragma unroll
        for (int qj = 0; qj < 2; ++qj)
          st[kvi][qj] = __builtin_amdgcn_mfma_f32_16x16x32_bf16(kf, qf[qj][ks], st[kvi][qj], 0, 0, 0);
      }

    // online softmax (state per q = qbase + qj*16 + lo, replicated over g)
    float corr2[2];
#pragma unroll
    for (int qj = 0; qj < 2; ++qj) {
      const int q = qbase + qj * 16 + lo;
      float tmax = -1e30f;
#pragma unroll
      for (int kvi = 0; kvi < 4; ++kvi)
#pragma unroll
        for (int r = 0; r < 4; ++r) {
          const int kv = kv0 + kvi * 16 + g * 4 + r;
          float s = st[kvi][qj][r] * 0.125f;
          s = (kv <= q) ? s : -1e30f;
          st[kvi][qj][r] = s;
          tmax = fmaxf(tmax, s);
        }
      tmax = fmaxf(tmax, __shfl_xor(tmax, 16));
      tmax = fmaxf(tmax, __shfl_xor(tmax, 32));
      const float mn = fmaxf(mo[qj], tmax);
      const float corr = __expf(mo[qj] - mn);
      mo[qj] = mn;
      float psum = 0.f;
#pragma unroll
      for (int kvi = 0; kvi < 4; ++kvi) {
        float p0 = __expf(st[kvi][qj][0] - mn);
        float p1 = __expf(st[kvi][qj][1] - mn);
        float p2 = __expf(st[kvi][qj][2] - mn);
        float p3 = __expf(st[kvi][qj][3] - mn);
        psum += (p0 + p1) + (p2 + p3);
        ushort4 pk;
        pk.x = f2bf(p0); pk.y = f2bf(p1); pk.z = f2bf(p2); pk.w = f2bf(p3);
        *(ushort4*)&Ps[w][qj * 16 + lo][kvi * 16 + g * 4] = pk;
      }
      psum += __shfl_xor(psum, 16);
      psum += __shfl_xor(psum, 32);
      ls[qj] = ls[qj] * corr + psum;
      corr2[qj] = corr;
    }

    // rescale O accumulator (O row q = qi*16 + g*4 + r; corr held by lane (g*4+r) slot qi)
#pragma unroll
    for (int qi = 0; qi < 2; ++qi)
#pragma unroll
      for (int r = 0; r < 4; ++r) {
        const float cc = __shfl(corr2[qi], g * 4 + r);
#pragma unroll
        for (int ni = 0; ni < 4; ++ni) oacc[qi][ni][r] *= cc;
      }

    asm volatile("" ::: "memory");  // order Ps writes (ushort4) vs reads (bf16x8)

    // PV: O[q][d] += P[q][kv] V[kv][d]
    bf16x8 pa[2][2];
#pragma unroll
    for (int qi = 0; qi < 2; ++qi)
#pragma unroll
      for (int ks = 0; ks < 2; ++ks)
        pa[qi][ks] = *(const bf16x8*)&Ps[w][qi * 16 + lo][ks * 32 + g * 8];
#pragma unroll
    for (int ks = 0; ks < 2; ++ks)
#pragma unroll
      for (int ni = 0; ni < 4; ++ni) {
        bf16x8 vb = *(const bf16x8*)&Vs[ni * 16 + lo][ks * 32 + g * 8];
#pragma unroll
        for (int qi = 0; qi < 2; ++qi)
          oacc[qi][ni] = __builtin_amdgcn_mfma_f32_16x16x32_bf16(pa[qi][ks], vb, oacc[qi][ni], 0, 0, 0);
      }
    __syncthreads();
  }

  // normalize + write
#pragma unroll
  for (int qi = 0; qi < 2; ++qi) {
    const float linv = 1.0f / ls[qi];
#pragma unroll
    for (int r = 0; r < 4; ++r) {
      const float li = __shfl(linv, g * 4 + r);
      const int q = qbase + qi * 16 + g * 4 + r;
      const size_t rowoff = (size_t)(b * 2048 + q) * 2048 + h * 64;
#pragma unroll
      for (int ni = 0; ni < 4; ++ni)
        O[rowoff + ni * 16 + lo] = f2bf(oacc[qi][ni][r] * li);
    }
  }
}

// ---------------------------------------------------------------- launch
extern "C" void kernel_launch(void* const* d_in, const int* in_sizes, int n_in,
                              void* d_out, int out_size, void* d_ws, size_t ws_size,
                              hipStream_t stream) {
  const float* x = (const float*)d_in[0];
  const float* wqkv = (const float*)d_in[1];
  const float* wo = (const float*)d_in[2];
  float* out = (float*)d_out;

  // workspace layout (elements of u16)
  u16* xb = (u16*)d_ws;                 //  8388608  (x bf16, later reused as attn_out)
  u16* wqkvb = xb + (size_t)8388608;    // 12582912
  u16* wob = wqkvb + (size_t)12582912;  //  4194304
  u16* qkv = wob + (size_t)4194304;     // 25165824
  u16* qr = qkv + (size_t)25165824;     //  8388608
  u16* kr = qr + (size_t)8388608;       //  8388608
  u16* vt = kr + (size_t)8388608;       //  8388608
  u16* aout = xb;                       // reuse x_bf16 region for attention output

  cvt_kernel<<<1024, 256, 0, stream>>>(x, xb, 8388608 / 4);
  cvt_kernel<<<1024, 256, 0, stream>>>(wqkv, wqkvb, 12582912 / 4);
  cvt_kernel<<<512, 256, 0, stream>>>(wo, wob, 4194304 / 4);

  // qkv = x @ wqkv^T : M=4096, N=6144, K=2048
  gemm_bt<1><<<dim3(48, 32), 256, 0, stream>>>(xb, wqkvb, qkv, 4096, 6144, 2048);

  // RoPE + split/transpose
  rope_kernel<<<dim3(64, 32), 256, 0, stream>>>(qkv, qr, kr, vt);

  // causal flash attention
  flash_kernel<<<dim3(16, 64), 256, 0, stream>>>(qr, kr, vt, aout);

  // out = attn @ wo^T : M=4096, N=2048, K=2048
  gemm_bt<0><<<dim3(16, 32), 256, 0, stream>>>(aout, wob, out, 4096, 2048, 2048);
}

// Round 2
// 440.812 us; speedup vs baseline: 1.1609x; 1.1609x over previous
//
#include <hip/hip_runtime.h>

using u16 = unsigned short;
using u32 = unsigned int;

typedef __attribute__((ext_vector_type(8))) __bf16 bf16x8;
typedef __attribute__((ext_vector_type(4))) __bf16 bf16x4;
typedef __attribute__((ext_vector_type(4))) float f32x4;

__device__ __forceinline__ u16 f2bf(float f) {
  u32 u = __builtin_bit_cast(u32, f);
  u = (u + 0x7fffu + ((u >> 16) & 1u)) >> 16;
  return (u16)u;
}
__device__ __forceinline__ float bf2f(u16 h) {
  u32 u = ((u32)h) << 16;
  return __builtin_bit_cast(float, u);
}

#if __has_builtin(__builtin_amdgcn_exp2f)
__device__ __forceinline__ float exp2_fast(float x) { return __builtin_amdgcn_exp2f(x); }
#else
__device__ __forceinline__ float exp2_fast(float x) {
  float r; asm("v_exp_f32 %0, %1" : "=v"(r) : "v"(x)); return r;
}
#endif

#define GLDS16(gp, lp)                                                              \
  __builtin_amdgcn_global_load_lds((const __attribute__((address_space(1))) void*)(gp), \
                                   (__attribute__((address_space(3))) void*)(lp), 16, 0, 0)

// ---------------------------------------------------------------- cvt fp32->bf16
__global__ void cvt_kernel(const float* __restrict__ in, u16* __restrict__ out, int n4) {
  int idx = blockIdx.x * blockDim.x + threadIdx.x;
  int stride = gridDim.x * blockDim.x;
  for (int i = idx; i < n4; i += stride) {
    float4 f = ((const float4*)in)[i];
    ushort4 o;
    o.x = f2bf(f.x); o.y = f2bf(f.y); o.z = f2bf(f.z); o.w = f2bf(f.w);
    ((ushort4*)out)[i] = o;
  }
}

// ---------------------------------------------------------------- GEMM C = A * B^T
// A: [M][K] bf16 row-major, B: [N][K] bf16 row-major, C: [M][N]
// 128x128 tile, BK=32, 256 threads = 4 waves (2x2 of 64x64). XCD-swizzled grid.
template <int OUT_BF16>
__global__ __launch_bounds__(256) void gemm_bt(const u16* __restrict__ A,
                                               const u16* __restrict__ B,
                                               void* __restrict__ Cv,
                                               int M, int N, int K) {
  __shared__ alignas(16) u16 As[128 * 32];
  __shared__ alignas(16) u16 Bs[128 * 32];
  const int tid = threadIdx.x;
  const int w = tid >> 6, lane = tid & 63;
  const int g = lane >> 4, lo = lane & 15;
  // bijective XCD swizzle (nwg % 8 == 0 for both launches)
  const int nwg = gridDim.x * gridDim.y;
  const int lid = blockIdx.y * gridDim.x + blockIdx.x;
  const int cpx = nwg >> 3;
  const int swz = (lid & 7) * cpx + (lid >> 3);
  const int bxs = swz % gridDim.x, bys = swz / gridDim.x;
  const int bm = bys * 128, bn = bxs * 128;
  const int wm = (w >> 1) * 64, wn = (w & 1) * 64;
  const int srow = lane >> 2;        // 0..15
  const int skp = (lane & 3) * 8;    // k offset of this lane's 16B
  f32x4 acc[4][4] = {};

  for (int k0 = 0; k0 < K; k0 += 32) {
#pragma unroll
    for (int c2 = 0; c2 < 2; ++c2) {
      const int c = 2 * w + c2;
      const int row = c * 16 + srow;
      const u16* ga = A + (size_t)(bm + row) * K + k0 + skp;
      const u16* gb = B + (size_t)(bn + row) * K + k0 + skp;
      GLDS16(ga, As + c * 512);
      GLDS16(gb, Bs + c * 512);
    }
    __syncthreads();
    bf16x8 af[4], bfr[4];
#pragma unroll
    for (int i = 0; i < 4; ++i) {
      af[i] = *(const bf16x8*)(As + (wm + i * 16 + lo) * 32 + g * 8);
      bfr[i] = *(const bf16x8*)(Bs + (wn + i * 16 + lo) * 32 + g * 8);
    }
#pragma unroll
    for (int i = 0; i < 4; ++i)
#pragma unroll
      for (int j = 0; j < 4; ++j)
        acc[i][j] = __builtin_amdgcn_mfma_f32_16x16x32_bf16(af[i], bfr[j], acc[i][j], 0, 0, 0);
    __syncthreads();
  }

#pragma unroll
  for (int i = 0; i < 4; ++i) {
#pragma unroll
    for (int r = 0; r < 4; ++r) {
      const int row = bm + wm + i * 16 + g * 4 + r;
#pragma unroll
      for (int j = 0; j < 4; ++j) {
        const int col = bn + wn + j * 16 + lo;
        float v = acc[i][j][r];
        if (OUT_BF16)
          ((u16*)Cv)[(size_t)row * N + col] = f2bf(v);
        else
          ((float*)Cv)[(size_t)row * N + col] = v;
      }
    }
  }
}

// ---------------------------------------------------------------- RoPE + layout
// qkv: [4096][6144] bf16. Q,K out: [64 bh][2048][64]; VT out: [64 bh][64 d][2048 l]
// Q is pre-scaled by 0.125*log2(e) so flash softmax runs in exp2 domain.
__global__ __launch_bounds__(256) void rope_kernel(const u16* __restrict__ qkv,
                                                   u16* __restrict__ Q,
                                                   u16* __restrict__ Ko,
                                                   u16* __restrict__ VT) {
  const int bh = blockIdx.x;  // 0..63
  const int lt = blockIdx.y;  // 0..31
  const int b = bh >> 5, h = bh & 31;
  const int tid = threadIdx.x;
  const int l0 = lt * 64;
  const float QSC = 0.18033688011f;  // 0.125 * log2(e)

  const int i = tid & 31;  // freq index (fixed per thread)
  const float invf = exp2f(-(float)i * 0.28125f);  // 512^(-i/32)
#pragma unroll
  for (int it = 0; it < 8; ++it) {
    const int l = (tid >> 5) + it * 8;  // 0..63
    const int m = b * 2048 + l0 + l;
    float s, c;
    __sincosf((float)(l0 + l) * invf, &s, &c);
    const int base = m * 6144 + h * 64 + i;
    float qlo = bf2f(qkv[base]), qhi = bf2f(qkv[base + 32]);
    float klo = bf2f(qkv[base + 2048]), khi = bf2f(qkv[base + 2048 + 32]);
    const int ob = (bh * 2048 + l0 + l) * 64 + i;
    Q[ob] = f2bf((qlo * c - qhi * s) * QSC);
    Q[ob + 32] = f2bf((qhi * c + qlo * s) * QSC);
    Ko[ob] = f2bf(klo * c - khi * s);
    Ko[ob + 32] = f2bf(khi * c + klo * s);
  }

  // V transpose via LDS: read [l][d] tile, write [d][l]
  __shared__ alignas(16) u16 vs[64][72];
#pragma unroll
  for (int it = 0; it < 2; ++it) {
    const int c = tid * 2 + it;  // 0..511 chunks of 8 elems
    const int l = c >> 3, off = (c & 7) * 8;
    const int m = b * 2048 + l0 + l;
    *(uint4*)&vs[l][off] = *(const uint4*)&qkv[m * 6144 + 4096 + h * 64 + off];
  }
  __syncthreads();
#pragma unroll
  for (int it = 0; it < 2; ++it) {
    const int c = tid * 2 + it;
    const int d = c >> 3, lc = (c & 7) * 8;
    u32 w0 = (u32)vs[lc + 0][d] | ((u32)vs[lc + 1][d] << 16);
    u32 w1 = (u32)vs[lc + 2][d] | ((u32)vs[lc + 3][d] << 16);
    u32 w2 = (u32)vs[lc + 4][d] | ((u32)vs[lc + 5][d] << 16);
    u32 w3 = (u32)vs[lc + 6][d] | ((u32)vs[lc + 7][d] << 16);
    uint4 pk; pk.x = w0; pk.y = w1; pk.z = w2; pk.w = w3;
    *(uint4*)&VT[(size_t)(bh * 64 + d) * 2048 + l0 + lc] = pk;
  }
}

// ---------------------------------------------------------------- flash attention (causal)
// Q,K: [64][2048][64] bf16; VT: [64][64][2048] bf16; O: [4096][2048]
// 512 blocks: block -> (bh, pair); processes q-tiles pair and 15-pair (34 kv-tiles, uniform).
// K/V double-buffered in LDS via global_load_lds with XOR-swizzled source; P stored in
// MFMA A-frag layout (per-lane-linear reads). One barrier per kv-tile.
__global__ __launch_bounds__(256) void flash_kernel(const u16* __restrict__ Q,
                                                    const u16* __restrict__ K,
                                                    const u16* __restrict__ V,
                                                    u16* __restrict__ O) {
  __shared__ alignas(16) u16 KVs[2][2][64][64];   // [buf][K/V][row][col], 32 KB
  __shared__ alignas(16) u16 Ps2[4][2][2][64][8]; // [w][qj][ks][lane][e], 16 KB
  const int bid = blockIdx.x;
  const int xcd = bid & 7, slot = bid >> 3;
  const int bh = xcd * 8 + (slot & 7);  // 8 bh per XCD -> K/V fits XCD L2
  const int pair = slot >> 3;           // 0..7
  const int b = bh >> 5, h = bh & 31;
  const int tid = threadIdx.x;
  const int w = tid >> 6, lane = tid & 63;
  const int g = lane >> 4, lo = lane & 15;
  const size_t bh2048 = (size_t)bh * 2048;
  const int srow = tid >> 3;  // 0..31
  const int sc8 = tid & 7;

  auto stage = [&](int buf, int kv0) {
#pragma unroll
    for (int p = 0; p < 2; ++p) {
      const int r = p * 32 + srow;                  // 0..63
      const int col8 = sc8 ^ (r & 7);               // pre-swizzled source col (8-elem units)
      const u16* gk = K + (bh2048 + kv0 + r) * 64 + col8 * 8;
      const u16* gv = V + ((size_t)bh * 64 + r) * 2048 + kv0 + col8 * 8;
      u16* lbase = &KVs[buf][0][0][0] + p * 2048 + w * 512;  // wave-uniform
      GLDS16(gk, lbase);
      GLDS16(gv, lbase + 4096);
    }
  };

  for (int seg = 0; seg < 2; ++seg) {
    const int qt = seg ? 15 - pair : pair;
    const int qbase = qt * 128 + w * 32;
    const int ntile = 2 * qt + 2;

    // Q fragments (B-operand of swapped QK^T), pre-scaled in rope
    bf16x8 qf[2][2];
#pragma unroll
    for (int qj = 0; qj < 2; ++qj)
#pragma unroll
      for (int ks = 0; ks < 2; ++ks)
        qf[qj][ks] = *(const bf16x8*)(Q + (bh2048 + qbase + qj * 16 + lo) * 64 + ks * 32 + g * 8);

    float mo[2] = {-1e30f, -1e30f};
    float ls[2] = {0.f, 0.f};
    f32x4 oacc[2][4] = {};

    stage(0, 0);
    __syncthreads();

    for (int t = 0; t < ntile; ++t) {
      const int cur = t & 1;
      const int kv0 = t * 64;
      if (t + 1 < ntile) stage(cur ^ 1, kv0 + 64);  // prefetch next tile (drained at barrier)

      // S^T[kv][q] = sum_d K[kv][d] Q[q][d]   (swizzled conflict-free reads)
      f32x4 st[4][2] = {};
#pragma unroll
      for (int kvi = 0; kvi < 4; ++kvi)
#pragma unroll
        for (int ks = 0; ks < 2; ++ks) {
          bf16x8 kf = *(const bf16x8*)&KVs[cur][0][kvi * 16 + lo][(ks * 32 + g * 8) ^ ((lo & 7) << 3)];
#pragma unroll
          for (int qj = 0; qj < 2; ++qj)
            st[kvi][qj] = __builtin_amdgcn_mfma_f32_16x16x32_bf16(kf, qf[qj][ks], st[kvi][qj], 0, 0, 0);
        }

      // online softmax (exp2 domain); P written directly in A-frag layout
      float corr2[2];
#pragma unroll
      for (int qj = 0; qj < 2; ++qj) {
        const int q = qbase + qj * 16 + lo;
        float tmax = -1e30f;
#pragma unroll
        for (int kvi = 0; kvi < 4; ++kvi)
#pragma unroll
          for (int r = 0; r < 4; ++r) {
            const int kv = kv0 + kvi * 16 + g * 4 + r;
            float s = st[kvi][qj][r];
            s = (kv <= q) ? s : -1e30f;
            st[kvi][qj][r] = s;
            tmax = fmaxf(tmax, s);
          }
        tmax = fmaxf(tmax, __shfl_xor(tmax, 16));
        tmax = fmaxf(tmax, __shfl_xor(tmax, 32));
        const float mn = fmaxf(mo[qj], tmax);
        const float corr = exp2_fast(mo[qj] - mn);
        mo[qj] = mn;
        float psum = 0.f;
#pragma unroll
        for (int kvi = 0; kvi < 4; ++kvi) {
          float p0 = exp2_fast(st[kvi][qj][0] - mn);
          float p1 = exp2_fast(st[kvi][qj][1] - mn);
          float p2 = exp2_fast(st[kvi][qj][2] - mn);
          float p3 = exp2_fast(st[kvi][qj][3] - mn);
          psum += (p0 + p1) + (p2 + p3);
          bf16x4 pk;
          pk[0] = (__bf16)p0; pk[1] = (__bf16)p1; pk[2] = (__bf16)p2; pk[3] = (__bf16)p3;
          // value (q, kv=kvi*16+g*4+r) -> frag slot: lane'=((kvi&1)*2+(g>>1))*16+lo, elem (g&1)*4+r
          *(bf16x4*)&Ps2[w][qj][kvi >> 1][((kvi & 1) * 2 + (g >> 1)) * 16 + lo][(g & 1) * 4] = pk;
        }
        psum += __shfl_xor(psum, 16);
        psum += __shfl_xor(psum, 32);
        ls[qj] = ls[qj] * corr + psum;
        corr2[qj] = corr;
      }

      // rescale O accumulator
#pragma unroll
      for (int qi = 0; qi < 2; ++qi)
#pragma unroll
        for (int r = 0; r < 4; ++r) {
          const float cc = __shfl(corr2[qi], g * 4 + r);
#pragma unroll
          for (int ni = 0; ni < 4; ++ni) oacc[qi][ni][r] *= cc;
        }

      asm volatile("" ::: "memory");

      // PV: O[q][d] += P[q][kv] V[kv][d]; P-frag reads are per-lane-linear (conflict-free)
      bf16x8 pa[2][2];
#pragma unroll
      for (int qi = 0; qi < 2; ++qi)
#pragma unroll
        for (int ks = 0; ks < 2; ++ks)
          pa[qi][ks] = *(const bf16x8*)&Ps2[w][qi][ks][lane][0];
#pragma unroll
      for (int ks = 0; ks < 2; ++ks)
#pragma unroll
        for (int ni = 0; ni < 4; ++ni) {
          bf16x8 vb = *(const bf16x8*)&KVs[cur][1][ni * 16 + lo][(ks * 32 + g * 8) ^ ((lo & 7) << 3)];
#pragma unroll
          for (int qi = 0; qi < 2; ++qi)
            oacc[qi][ni] = __builtin_amdgcn_mfma_f32_16x16x32_bf16(pa[qi][ks], vb, oacc[qi][ni], 0, 0, 0);
        }
      __syncthreads();
    }

    // normalize + write
#pragma unroll
    for (int qi = 0; qi < 2; ++qi) {
      const float linv = 1.0f / ls[qi];
#pragma unroll
      for (int r = 0; r < 4; ++r) {
        const float li = __shfl(linv, g * 4 + r);
        const int q = qbase + qi * 16 + g * 4 + r;
        const size_t rowoff = (size_t)(b * 2048 + q) * 2048 + h * 64;
#pragma unroll
        for (int ni = 0; ni < 4; ++ni)
          O[rowoff + ni * 16 + lo] = f2bf(oacc[qi][ni][r] * li);
      }
    }
  }
}

// ---------------------------------------------------------------- launch
extern "C" void kernel_launch(void* const* d_in, const int* in_sizes, int n_in,
                              void* d_out, int out_size, void* d_ws, size_t ws_size,
                              hipStream_t stream) {
  const float* x = (const float*)d_in[0];
  const float* wqkv = (const float*)d_in[1];
  const float* wo = (const float*)d_in[2];
  float* out = (float*)d_out;

  // workspace layout (elements of u16)
  u16* xb = (u16*)d_ws;                 //  8388608  (x bf16, later reused as attn_out)
  u16* wqkvb = xb + (size_t)8388608;    // 12582912
  u16* wob = wqkvb + (size_t)12582912;  //  4194304
  u16* qkv = wob + (size_t)4194304;     // 25165824
  u16* qr = qkv + (size_t)25165824;     //  8388608
  u16* kr = qr + (size_t)8388608;       //  8388608
  u16* vt = kr + (size_t)8388608;       //  8388608
  u16* aout = xb;                       // reuse x_bf16 region for attention output

  cvt_kernel<<<1024, 256, 0, stream>>>(x, xb, 8388608 / 4);
  cvt_kernel<<<1024, 256, 0, stream>>>(wqkv, wqkvb, 12582912 / 4);
  cvt_kernel<<<512, 256, 0, stream>>>(wo, wob, 4194304 / 4);

  // qkv = x @ wqkv^T : M=4096, N=6144, K=2048
  gemm_bt<1><<<dim3(48, 32), 256, 0, stream>>>(xb, wqkvb, qkv, 4096, 6144, 2048);

  // RoPE + split/transpose (Q pre-scaled for exp2-domain softmax)
  rope_kernel<<<dim3(64, 32), 256, 0, stream>>>(qkv, qr, kr, vt);

  // causal flash attention: 512 blocks, paired q-tiles, XCD-grouped by bh
  flash_kernel<<<dim3(512), 256, 0, stream>>>(qr, kr, vt, aout);

  // out = attn @ wo^T : M=4096, N=2048, K=2048
  gemm_bt<0><<<dim3(16, 32), 256, 0, stream>>>(aout, wob, out, 4096, 2048, 2048);
}

// Round 3
// 403.730 us; speedup vs baseline: 1.2675x; 1.0918x over previous
//
#include <hip/hip_runtime.h>

using u16 = unsigned short;
using u32 = unsigned int;

typedef __attribute__((ext_vector_type(8))) __bf16 bf16x8;
typedef __attribute__((ext_vector_type(4))) __bf16 bf16x4;
typedef __attribute__((ext_vector_type(4))) float f32x4;

__device__ __forceinline__ u16 f2bf(float f) {
  u32 u = __builtin_bit_cast(u32, f);
  u = (u + 0x7fffu + ((u >> 16) & 1u)) >> 16;
  return (u16)u;
}
__device__ __forceinline__ float bf2f(u16 h) {
  u32 u = ((u32)h) << 16;
  return __builtin_bit_cast(float, u);
}

__device__ __forceinline__ float exp2_fast(float x) {
  float r; asm("v_exp_f32 %0, %1" : "=v"(r) : "v"(x)); return r;
}

#define GLDS16(gp, lp)                                                              \
  __builtin_amdgcn_global_load_lds((const __attribute__((address_space(1))) void*)(gp), \
                                   (__attribute__((address_space(3))) void*)(lp), 16, 0, 0)

// ---------------------------------------------------------------- cvt fp32->bf16
__global__ void cvt_kernel(const float* __restrict__ in, u16* __restrict__ out, int n4) {
  int idx = blockIdx.x * blockDim.x + threadIdx.x;
  int stride = gridDim.x * blockDim.x;
  for (int i = idx; i < n4; i += stride) {
    float4 f = ((const float4*)in)[i];
    ushort4 o;
    o.x = f2bf(f.x); o.y = f2bf(f.y); o.z = f2bf(f.z); o.w = f2bf(f.w);
    ((ushort4*)out)[i] = o;
  }
}

// ---------------------------------------------------------------- GEMM C = A * B^T (256^2, 8-phase)
// A: [M][K] bf16, B: [N][K] bf16, C: [M][N]. BM=BN=256, BK=64, 512 thr = 8 waves (2Mx4N).
// LDS: As[2][256][64] @0, Bs[2][256][64] @32768 (128 KiB dynamic).
// 16B-chunk XOR swizzle (c ^ (row&7)) applied to BOTH gload source and ds_read addr.
// Stage slots/iter i: ph1,2 A1<-2i+1 | ph3,4 B0<-2i+2 | ph5,6 A0<-2i+2 | ph7,8 B1<-2i+3.
// Waits: vmcnt(4) at ph4 (odd tile ready) and ph8 (next even tile ready); vmcnt(0) at last ph4.
template <int OUT_BF16>
__global__ __launch_bounds__(512, 2) void gemm256(const u16* __restrict__ A,
                                                  const u16* __restrict__ B,
                                                  void* __restrict__ Cv,
                                                  int M, int N, int K) {
  extern __shared__ u16 lds[];
  const int tid = threadIdx.x;
  const int w = tid >> 6, lane = tid & 63;
  const int g = lane >> 4, lo = lane & 15;
  const int wm = (w >> 2) * 128, wn = (w & 3) * 64;
  const int nwg = gridDim.x * gridDim.y;
  const int lid = blockIdx.y * gridDim.x + blockIdx.x;
  const int cpx = nwg >> 3;
  const int swz = (lid & 7) * cpx + (lid >> 3);  // bijective: nwg % 8 == 0
  const int bxs = swz % gridDim.x, bys = swz / gridDim.x;
  const int bm = bys * 256, bn = bxs * 256;
  const int NT = K >> 6;

  auto stage_half = [&](int mat, int buf, int half, int kt) {
    if (kt >= NT) return;
    const u16* src = mat ? B : A;
    const int rbase = (mat ? bn : bm) + half * 128;
    u16* lbase0 = lds + mat * 32768 + buf * 16384 + half * 8192;
#pragma unroll
    for (int j = 0; j < 2; ++j) {
      const int f = j * 512 + tid;
      const int rl = f >> 3, cl = f & 7;
      const int cg = cl ^ (rl & 7);  // pre-swizzled source chunk
      const u16* gp = src + (size_t)(rbase + rl) * K + kt * 64 + cg * 8;
      GLDS16(gp, lbase0 + (j * 512 + w * 64) * 8);
    }
  };
  auto lda = [&](int buf, int q, int m2, int ks) -> bf16x8 {
    const int row = wm + q * 32 + m2 * 16 + lo;
    const int cl = (ks * 4 + g) ^ (row & 7);
    return *(const bf16x8*)(lds + buf * 16384 + row * 64 + cl * 8);
  };
  auto ldb = [&](int buf, int n, int ks) -> bf16x8 {
    const int row = wn + n * 16 + lo;
    const int cl = (ks * 4 + g) ^ (row & 7);
    return *(const bf16x8*)(lds + 32768 + buf * 16384 + row * 64 + cl * 8);
  };

  f32x4 acc[8][4] = {};
  bf16x8 bfrag[4][2];

#define PHASE(buf, q, LDB, smat, sbuf, shalf, stile, vm)                                    \
  do {                                                                                      \
    bf16x8 af[2][2];                                                                        \
    _Pragma("unroll") for (int m2_ = 0; m2_ < 2; ++m2_)                                     \
    _Pragma("unroll") for (int ks_ = 0; ks_ < 2; ++ks_)                                     \
      af[m2_][ks_] = lda(buf, q, m2_, ks_);                                                 \
    if (LDB) {                                                                              \
      _Pragma("unroll") for (int n_ = 0; n_ < 4; ++n_)                                      \
      _Pragma("unroll") for (int ks_ = 0; ks_ < 2; ++ks_)                                   \
        bfrag[n_][ks_] = ldb(buf, n_, ks_);                                                 \
    }                                                                                       \
    stage_half(smat, sbuf, shalf, stile);                                                   \
    if ((vm) == 4) asm volatile("s_waitcnt vmcnt(4)");                                      \
    else if ((vm) == 0) asm volatile("s_waitcnt vmcnt(0)");                                 \
    __builtin_amdgcn_s_barrier();                                                           \
    asm volatile("s_waitcnt lgkmcnt(0)");                                                   \
    __builtin_amdgcn_sched_barrier(0);                                                      \
    __builtin_amdgcn_s_setprio(1);                                                          \
    _Pragma("unroll") for (int m2_ = 0; m2_ < 2; ++m2_)                                     \
    _Pragma("unroll") for (int n_ = 0; n_ < 4; ++n_)                                        \
    _Pragma("unroll") for (int ks_ = 0; ks_ < 2; ++ks_)                                     \
      acc[(q) * 2 + m2_][n_] = __builtin_amdgcn_mfma_f32_16x16x32_bf16(                     \
          af[m2_][ks_], bfrag[n_][ks_], acc[(q) * 2 + m2_][n_], 0, 0, 0);                   \
    __builtin_amdgcn_s_setprio(0);                                                          \
    __builtin_amdgcn_sched_barrier(0);                                                      \
    __builtin_amdgcn_s_barrier();                                                           \
  } while (0)

  // prologue: B0<-t0, A0<-t0, B1<-t1 (6 half-stages = 12 loads/wave)
  stage_half(1, 0, 0, 0); stage_half(1, 0, 1, 0);
  stage_half(0, 0, 0, 0); stage_half(0, 0, 1, 0);
  stage_half(1, 1, 0, 1); stage_half(1, 1, 1, 1);
  asm volatile("s_waitcnt vmcnt(4)");  // tile0 (B0,A0) landed
  __builtin_amdgcn_s_barrier();

  const int NITER = NT >> 1;
  for (int i = 0; i < NITER - 1; ++i) {
    const int to = 2 * i + 1, te = 2 * i + 2, tn = 2 * i + 3;
    PHASE(0, 0, 1, 0, 1, 0, to, -1);
    PHASE(0, 1, 0, 0, 1, 1, to, -1);
    PHASE(0, 2, 0, 1, 0, 0, te, -1);
    PHASE(0, 3, 0, 1, 0, 1, te, 4);
    PHASE(1, 0, 1, 0, 0, 0, te, -1);
    PHASE(1, 1, 0, 0, 0, 1, te, -1);
    PHASE(1, 2, 0, 1, 1, 0, tn, -1);
    PHASE(1, 3, 0, 1, 1, 1, tn, 4);
  }
  {  // last iteration: only A1<-(NT-1) staged; drain at ph4
    const int to = NT - 1;
    PHASE(0, 0, 1, 0, 1, 0, to, -1);
    PHASE(0, 1, 0, 0, 1, 1, to, -1);
    PHASE(0, 2, 0, 1, 0, 0, NT, -1);
    PHASE(0, 3, 0, 1, 0, 1, NT, 0);
    PHASE(1, 0, 1, 0, 0, 0, NT, -1);
    PHASE(1, 1, 0, 0, 0, 1, NT, -1);
    PHASE(1, 2, 0, 1, 1, 0, NT, -1);
    PHASE(1, 3, 0, 1, 1, 1, NT, -1);
  }
#undef PHASE

#pragma unroll
  for (int m = 0; m < 8; ++m)
#pragma unroll
    for (int r = 0; r < 4; ++r) {
      const int row = bm + wm + m * 16 + g * 4 + r;
#pragma unroll
      for (int n = 0; n < 4; ++n) {
        const int col = bn + wn + n * 16 + lo;
        float v = acc[m][n][r];
        if (OUT_BF16) ((u16*)Cv)[(size_t)row * N + col] = f2bf(v);
        else ((float*)Cv)[(size_t)row * N + col] = v;
      }
    }
}

// ---------------------------------------------------------------- RoPE + layout
__global__ __launch_bounds__(256) void rope_kernel(const u16* __restrict__ qkv,
                                                   u16* __restrict__ Q,
                                                   u16* __restrict__ Ko,
                                                   u16* __restrict__ VT) {
  const int bh = blockIdx.x;
  const int lt = blockIdx.y;
  const int b = bh >> 5, h = bh & 31;
  const int tid = threadIdx.x;
  const int l0 = lt * 64;
  const float QSC = 0.18033688011f;  // 0.125 * log2(e)

  const int i = tid & 31;
  const float invf = exp2f(-(float)i * 0.28125f);
#pragma unroll
  for (int it = 0; it < 8; ++it) {
    const int l = (tid >> 5) + it * 8;
    const int m = b * 2048 + l0 + l;
    float s, c;
    __sincosf((float)(l0 + l) * invf, &s, &c);
    const int base = m * 6144 + h * 64 + i;
    float qlo = bf2f(qkv[base]), qhi = bf2f(qkv[base + 32]);
    float klo = bf2f(qkv[base + 2048]), khi = bf2f(qkv[base + 2048 + 32]);
    const int ob = (bh * 2048 + l0 + l) * 64 + i;
    Q[ob] = f2bf((qlo * c - qhi * s) * QSC);
    Q[ob + 32] = f2bf((qhi * c + qlo * s) * QSC);
    Ko[ob] = f2bf(klo * c - khi * s);
    Ko[ob + 32] = f2bf(khi * c + klo * s);
  }

  __shared__ alignas(16) u16 vs[64][72];
#pragma unroll
  for (int it = 0; it < 2; ++it) {
    const int c = tid * 2 + it;
    const int l = c >> 3, off = (c & 7) * 8;
    const int m = b * 2048 + l0 + l;
    *(uint4*)&vs[l][off] = *(const uint4*)&qkv[m * 6144 + 4096 + h * 64 + off];
  }
  __syncthreads();
#pragma unroll
  for (int it = 0; it < 2; ++it) {
    const int c = tid * 2 + it;
    const int d = c >> 3, lc = (c & 7) * 8;
    u32 w0 = (u32)vs[lc + 0][d] | ((u32)vs[lc + 1][d] << 16);
    u32 w1 = (u32)vs[lc + 2][d] | ((u32)vs[lc + 3][d] << 16);
    u32 w2 = (u32)vs[lc + 4][d] | ((u32)vs[lc + 5][d] << 16);
    u32 w3 = (u32)vs[lc + 6][d] | ((u32)vs[lc + 7][d] << 16);
    uint4 pk; pk.x = w0; pk.y = w1; pk.z = w2; pk.w = w3;
    *(uint4*)&VT[(size_t)(bh * 64 + d) * 2048 + l0 + lc] = pk;
  }
}

// ---------------------------------------------------------------- flash attention (causal)
__global__ __launch_bounds__(256) void flash_kernel(const u16* __restrict__ Q,
                                                    const u16* __restrict__ K,
                                                    const u16* __restrict__ V,
                                                    u16* __restrict__ O) {
  __shared__ alignas(16) u16 KVs[2][2][64][64];
  __shared__ alignas(16) u16 Ps2[4][2][2][64][8];
  const int bid = blockIdx.x;
  const int xcd = bid & 7, slot = bid >> 3;
  const int bh = xcd * 8 + (slot & 7);
  const int pair = slot >> 3;
  const int b = bh >> 5, h = bh & 31;
  const int tid = threadIdx.x;
  const int w = tid >> 6, lane = tid & 63;
  const int g = lane >> 4, lo = lane & 15;
  const size_t bh2048 = (size_t)bh * 2048;
  const int srow = tid >> 3;
  const int sc8 = tid & 7;

  auto stage = [&](int buf, int kv0) {
#pragma unroll
    for (int p = 0; p < 2; ++p) {
      const int r = p * 32 + srow;
      const int col8 = sc8 ^ (r & 7);
      const u16* gk = K + (bh2048 + kv0 + r) * 64 + col8 * 8;
      const u16* gv = V + ((size_t)bh * 64 + r) * 2048 + kv0 + col8 * 8;
      u16* lbase = &KVs[buf][0][0][0] + p * 2048 + w * 512;
      GLDS16(gk, lbase);
      GLDS16(gv, lbase + 4096);
    }
  };

  for (int seg = 0; seg < 2; ++seg) {
    const int qt = seg ? 15 - pair : pair;
    const int qbase = qt * 128 + w * 32;
    const int ntile = 2 * qt + 2;

    bf16x8 qf[2][2];
#pragma unroll
    for (int qj = 0; qj < 2; ++qj)
#pragma unroll
      for (int ks = 0; ks < 2; ++ks)
        qf[qj][ks] = *(const bf16x8*)(Q + (bh2048 + qbase + qj * 16 + lo) * 64 + ks * 32 + g * 8);

    float mo[2] = {-1e30f, -1e30f};
    float ls[2] = {0.f, 0.f};
    f32x4 oacc[2][4] = {};

    stage(0, 0);
    __syncthreads();

    for (int t = 0; t < ntile; ++t) {
      const int cur = t & 1;
      const int kv0 = t * 64;
      if (t + 1 < ntile) stage(cur ^ 1, kv0 + 64);

      f32x4 st[4][2] = {};
#pragma unroll
      for (int kvi = 0; kvi < 4; ++kvi)
#pragma unroll
        for (int ks = 0; ks < 2; ++ks) {
          bf16x8 kf = *(const bf16x8*)&KVs[cur][0][kvi * 16 + lo][(ks * 32 + g * 8) ^ ((lo & 7) << 3)];
#pragma unroll
          for (int qj = 0; qj < 2; ++qj)
            st[kvi][qj] = __builtin_amdgcn_mfma_f32_16x16x32_bf16(kf, qf[qj][ks], st[kvi][qj], 0, 0, 0);
        }

      float corr2[2];
#pragma unroll
      for (int qj = 0; qj < 2; ++qj) {
        const int q = qbase + qj * 16 + lo;
        float tmax = -1e30f;
#pragma unroll
        for (int kvi = 0; kvi < 4; ++kvi)
#pragma unroll
          for (int r = 0; r < 4; ++r) {
            const int kv = kv0 + kvi * 16 + g * 4 + r;
            float s = st[kvi][qj][r];
            s = (kv <= q) ? s : -1e30f;
            st[kvi][qj][r] = s;
            tmax = fmaxf(tmax, s);
          }
        tmax = fmaxf(tmax, __shfl_xor(tmax, 16));
        tmax = fmaxf(tmax, __shfl_xor(tmax, 32));
        const float mn = fmaxf(mo[qj], tmax);
        const float corr = exp2_fast(mo[qj] - mn);
        mo[qj] = mn;
        float psum = 0.f;
#pragma unroll
        for (int kvi = 0; kvi < 4; ++kvi) {
          float p0 = exp2_fast(st[kvi][qj][0] - mn);
          float p1 = exp2_fast(st[kvi][qj][1] - mn);
          float p2 = exp2_fast(st[kvi][qj][2] - mn);
          float p3 = exp2_fast(st[kvi][qj][3] - mn);
          psum += (p0 + p1) + (p2 + p3);
          bf16x4 pk;
          pk[0] = (__bf16)p0; pk[1] = (__bf16)p1; pk[2] = (__bf16)p2; pk[3] = (__bf16)p3;
          *(bf16x4*)&Ps2[w][qj][kvi >> 1][((kvi & 1) * 2 + (g >> 1)) * 16 + lo][(g & 1) * 4] = pk;
        }
        psum += __shfl_xor(psum, 16);
        psum += __shfl_xor(psum, 32);
        ls[qj] = ls[qj] * corr + psum;
        corr2[qj] = corr;
      }

#pragma unroll
      for (int qi = 0; qi < 2; ++qi)
#pragma unroll
        for (int r = 0; r < 4; ++r) {
          const float cc = __shfl(corr2[qi], g * 4 + r);
#pragma unroll
          for (int ni = 0; ni < 4; ++ni) oacc[qi][ni][r] *= cc;
        }

      asm volatile("" ::: "memory");

      bf16x8 pa[2][2];
#pragma unroll
      for (int qi = 0; qi < 2; ++qi)
#pragma unroll
        for (int ks = 0; ks < 2; ++ks)
          pa[qi][ks] = *(const bf16x8*)&Ps2[w][qi][ks][lane][0];
#pragma unroll
      for (int ks = 0; ks < 2; ++ks)
#pragma unroll
        for (int ni = 0; ni < 4; ++ni) {
          bf16x8 vb = *(const bf16x8*)&KVs[cur][1][ni * 16 + lo][(ks * 32 + g * 8) ^ ((lo & 7) << 3)];
#pragma unroll
          for (int qi = 0; qi < 2; ++qi)
            oacc[qi][ni] = __builtin_amdgcn_mfma_f32_16x16x32_bf16(pa[qi][ks], vb, oacc[qi][ni], 0, 0, 0);
        }
      __syncthreads();
    }

#pragma unroll
    for (int qi = 0; qi < 2; ++qi) {
      const float linv = 1.0f / ls[qi];
#pragma unroll
      for (int r = 0; r < 4; ++r) {
        const float li = __shfl(linv, g * 4 + r);
        const int q = qbase + qi * 16 + g * 4 + r;
        const size_t rowoff = (size_t)(b * 2048 + q) * 2048 + h * 64;
#pragma unroll
        for (int ni = 0; ni < 4; ++ni)
          O[rowoff + ni * 16 + lo] = f2bf(oacc[qi][ni][r] * li);
      }
    }
  }
}

// ---------------------------------------------------------------- launch
extern "C" void kernel_launch(void* const* d_in, const int* in_sizes, int n_in,
                              void* d_out, int out_size, void* d_ws, size_t ws_size,
                              hipStream_t stream) {
  const float* x = (const float*)d_in[0];
  const float* wqkv = (const float*)d_in[1];
  const float* wo = (const float*)d_in[2];
  float* out = (float*)d_out;

  u16* xb = (u16*)d_ws;
  u16* wqkvb = xb + (size_t)8388608;
  u16* wob = wqkvb + (size_t)12582912;
  u16* qkv = wob + (size_t)4194304;
  u16* qr = qkv + (size_t)25165824;
  u16* kr = qr + (size_t)8388608;
  u16* vt = kr + (size_t)8388608;
  u16* aout = xb;

  hipFuncSetAttribute((const void*)gemm256<1>, hipFuncAttributeMaxDynamicSharedMemorySize, 131072);
  hipFuncSetAttribute((const void*)gemm256<0>, hipFuncAttributeMaxDynamicSharedMemorySize, 131072);

  cvt_kernel<<<1024, 256, 0, stream>>>(x, xb, 8388608 / 4);
  cvt_kernel<<<1024, 256, 0, stream>>>(wqkv, wqkvb, 12582912 / 4);
  cvt_kernel<<<512, 256, 0, stream>>>(wo, wob, 4194304 / 4);

  // qkv = x @ wqkv^T : M=4096, N=6144, K=2048
  gemm256<1><<<dim3(24, 16), 512, 131072, stream>>>(xb, wqkvb, qkv, 4096, 6144, 2048);

  // RoPE + split/transpose
  rope_kernel<<<dim3(64, 32), 256, 0, stream>>>(qkv, qr, kr, vt);

  // causal flash attention
  flash_kernel<<<dim3(512), 256, 0, stream>>>(qr, kr, vt, aout);

  // out = attn @ wo^T : M=4096, N=2048, K=2048
  gemm256<0><<<dim3(8, 16), 512, 131072, stream>>>(aout, wob, out, 4096, 2048, 2048);
}

// Round 4
// 380.996 us; speedup vs baseline: 1.3431x; 1.0597x over previous
//
#include <hip/hip_runtime.h>

using u16 = unsigned short;
using u32 = unsigned int;

typedef __attribute__((ext_vector_type(8))) __bf16 bf16x8;
typedef __attribute__((ext_vector_type(4))) __bf16 bf16x4;
typedef __attribute__((ext_vector_type(4))) float f32x4;

__device__ __forceinline__ u16 f2bf(float f) {
  u32 u = __builtin_bit_cast(u32, f);
  u = (u + 0x7fffu + ((u >> 16) & 1u)) >> 16;
  return (u16)u;
}
__device__ __forceinline__ float bf2f(u16 h) {
  u32 u = ((u32)h) << 16;
  return __builtin_bit_cast(float, u);
}

__device__ __forceinline__ float exp2_fast(float x) {
  float r; asm("v_exp_f32 %0, %1" : "=v"(r) : "v"(x)); return r;
}

#define GLDS16(gp, lp)                                                              \
  __builtin_amdgcn_global_load_lds((const __attribute__((address_space(1))) void*)(gp), \
                                   (__attribute__((address_space(3))) void*)(lp), 16, 0, 0)

// ---------------------------------------------------------------- cvt fp32->bf16
__global__ void cvt_kernel(const float* __restrict__ in, u16* __restrict__ out, int n4) {
  int idx = blockIdx.x * blockDim.x + threadIdx.x;
  int stride = gridDim.x * blockDim.x;
  for (int i = idx; i < n4; i += stride) {
    float4 f = ((const float4*)in)[i];
    ushort4 o;
    o.x = f2bf(f.x); o.y = f2bf(f.y); o.z = f2bf(f.z); o.w = f2bf(f.w);
    ((ushort4*)out)[i] = o;
  }
}

// ---------------------------------------------------------------- GEMM C = A * B^T (8-phase)
// A: [M][K] bf16, B: [N][K] bf16, C: [M][N]. BM=256, BN=NB*64, BK=64, 512 thr = 8 waves (2Mx4N).
// LDS: As[2][256][64] @0, Bs[2][BN][64] @32768elems. 16B-chunk XOR swizzle both sides.
// Slots/iter: ph1,2 A1<-2i+1 | ph3,4 B0<-2i+2 | ph5,6 A0<-2i+2 | ph7,8 B1<-2i+3.
// Waits: vmcnt(NB) at ph4/ph8 (2 half-tiles in flight); vmcnt(0) at last ph4.
template <int OUT_BF16, int NB>
__global__ __launch_bounds__(512, 2) void gemm256(const u16* __restrict__ A,
                                                  const u16* __restrict__ B,
                                                  void* __restrict__ Cv,
                                                  int M, int N, int K) {
  extern __shared__ u16 lds[];
  const int tid = threadIdx.x;
  const int w = tid >> 6, lane = tid & 63;
  const int g = lane >> 4, lo = lane & 15;
  const int wm = (w >> 2) * 128, wn = (w & 3) * (NB * 16);
  const int nwg = gridDim.x * gridDim.y;
  const int lid = blockIdx.y * gridDim.x + blockIdx.x;
  const int cpx = nwg >> 3;
  const int swz = (lid & 7) * cpx + (lid >> 3);  // bijective: nwg % 8 == 0
  const int bxs = swz % gridDim.x, bys = swz / gridDim.x;
  const int bm = bys * 256, bn = bxs * (NB * 64);
  const int NT = K >> 6;

  auto stage_half = [&](int mat, int buf, int half, int kt) {
    if (kt >= NT) return;
    const int rows_half = mat ? NB * 32 : 128;
    const int nloads = rows_half >> 6;
    const u16* src = mat ? B : A;
    const int rbase = (mat ? bn : bm) + half * rows_half;
    u16* lbase0 = lds + (mat ? 32768 + buf * (NB * 4096) : buf * 16384) + half * rows_half * 64;
#pragma unroll
    for (int j = 0; j < nloads; ++j) {
      const int f = j * 512 + tid;
      const int rl = f >> 3, cl = f & 7;
      const int cg = cl ^ (rl & 7);  // pre-swizzled source chunk
      const u16* gp = src + (size_t)(rbase + rl) * K + kt * 64 + cg * 8;
      GLDS16(gp, lbase0 + (j * 512 + w * 64) * 8);
    }
  };
  auto lda = [&](int buf, int q, int m2, int ks) -> bf16x8 {
    const int row = wm + q * 32 + m2 * 16 + lo;
    const int cl = (ks * 4 + g) ^ (row & 7);
    return *(const bf16x8*)(lds + buf * 16384 + row * 64 + cl * 8);
  };
  auto ldb = [&](int buf, int n, int ks) -> bf16x8 {
    const int row = wn + n * 16 + lo;
    const int cl = (ks * 4 + g) ^ (row & 7);
    return *(const bf16x8*)(lds + 32768 + buf * (NB * 4096) + row * 64 + cl * 8);
  };

  f32x4 acc[8][NB] = {};
  bf16x8 bfrag[NB][2];

#define PHASE(buf, q, LDB, smat, sbuf, shalf, stile, vm)                                    \
  do {                                                                                      \
    bf16x8 af[2][2];                                                                        \
    _Pragma("unroll") for (int m2_ = 0; m2_ < 2; ++m2_)                                     \
    _Pragma("unroll") for (int ks_ = 0; ks_ < 2; ++ks_)                                     \
      af[m2_][ks_] = lda(buf, q, m2_, ks_);                                                 \
    if (LDB) {                                                                              \
      _Pragma("unroll") for (int n_ = 0; n_ < NB; ++n_)                                     \
      _Pragma("unroll") for (int ks_ = 0; ks_ < 2; ++ks_)                                   \
        bfrag[n_][ks_] = ldb(buf, n_, ks_);                                                 \
    }                                                                                       \
    stage_half(smat, sbuf, shalf, stile);                                                   \
    if ((vm) == 0) asm volatile("s_waitcnt vmcnt(0)");                                      \
    else if ((vm) == 2) asm volatile("s_waitcnt vmcnt(2)");                                 \
    else if ((vm) == 4) asm volatile("s_waitcnt vmcnt(4)");                                 \
    if (LDB) asm volatile("s_waitcnt lgkmcnt(8)");                                          \
    __builtin_amdgcn_s_barrier();                                                           \
    asm volatile("s_waitcnt lgkmcnt(0)");                                                   \
    __builtin_amdgcn_sched_barrier(0);                                                      \
    __builtin_amdgcn_s_setprio(1);                                                          \
    _Pragma("unroll") for (int m2_ = 0; m2_ < 2; ++m2_)                                     \
    _Pragma("unroll") for (int n_ = 0; n_ < NB; ++n_)                                       \
    _Pragma("unroll") for (int ks_ = 0; ks_ < 2; ++ks_)                                     \
      acc[(q) * 2 + m2_][n_] = __builtin_amdgcn_mfma_f32_16x16x32_bf16(                     \
          af[m2_][ks_], bfrag[n_][ks_], acc[(q) * 2 + m2_][n_], 0, 0, 0);                   \
    __builtin_amdgcn_s_setprio(0);                                                          \
    __builtin_amdgcn_sched_barrier(0);                                                      \
    __builtin_amdgcn_s_barrier();                                                           \
  } while (0)

  // prologue: B0<-t0, A0<-t0, B1<-t1
  stage_half(1, 0, 0, 0); stage_half(1, 0, 1, 0);
  stage_half(0, 0, 0, 0); stage_half(0, 0, 1, 0);
  stage_half(1, 1, 0, 1); stage_half(1, 1, 1, 1);
  if (NB == 4) asm volatile("s_waitcnt vmcnt(4)");
  else asm volatile("s_waitcnt vmcnt(2)");
  __builtin_amdgcn_s_barrier();

  const int NITER = NT >> 1;
  for (int i = 0; i < NITER - 1; ++i) {
    const int to = 2 * i + 1, te = 2 * i + 2, tn = 2 * i + 3;
    PHASE(0, 0, 1, 0, 1, 0, to, -1);
    PHASE(0, 1, 0, 0, 1, 1, to, -1);
    PHASE(0, 2, 0, 1, 0, 0, te, -1);
    PHASE(0, 3, 0, 1, 0, 1, te, NB);
    PHASE(1, 0, 1, 0, 0, 0, te, -1);
    PHASE(1, 1, 0, 0, 0, 1, te, -1);
    PHASE(1, 2, 0, 1, 1, 0, tn, -1);
    PHASE(1, 3, 0, 1, 1, 1, tn, NB);
  }
  {  // last iteration
    const int to = NT - 1;
    PHASE(0, 0, 1, 0, 1, 0, to, -1);
    PHASE(0, 1, 0, 0, 1, 1, to, -1);
    PHASE(0, 2, 0, 1, 0, 0, NT, -1);
    PHASE(0, 3, 0, 1, 0, 1, NT, 0);
    PHASE(1, 0, 1, 0, 0, 0, NT, -1);
    PHASE(1, 1, 0, 0, 0, 1, NT, -1);
    PHASE(1, 2, 0, 1, 1, 0, NT, -1);
    PHASE(1, 3, 0, 1, 1, 1, NT, -1);
  }
#undef PHASE

#pragma unroll
  for (int m = 0; m < 8; ++m)
#pragma unroll
    for (int r = 0; r < 4; ++r) {
      const int row = bm + wm + m * 16 + g * 4 + r;
#pragma unroll
      for (int n = 0; n < NB; ++n) {
        const int col = bn + wn + n * 16 + lo;
        float v = acc[m][n][r];
        if (OUT_BF16) ((u16*)Cv)[(size_t)row * N + col] = f2bf(v);
        else ((float*)Cv)[(size_t)row * N + col] = v;
      }
    }
}

// ---------------------------------------------------------------- RoPE + layout
__global__ __launch_bounds__(256) void rope_kernel(const u16* __restrict__ qkv,
                                                   u16* __restrict__ Q,
                                                   u16* __restrict__ Ko,
                                                   u16* __restrict__ VT) {
  const int bh = blockIdx.x;
  const int lt = blockIdx.y;
  const int b = bh >> 5, h = bh & 31;
  const int tid = threadIdx.x;
  const int l0 = lt * 64;
  const float QSC = 0.18033688011f;  // 0.125 * log2(e)

  const int i = tid & 31;
  const float invf = exp2f(-(float)i * 0.28125f);
#pragma unroll
  for (int it = 0; it < 8; ++it) {
    const int l = (tid >> 5) + it * 8;
    const int m = b * 2048 + l0 + l;
    float s, c;
    __sincosf((float)(l0 + l) * invf, &s, &c);
    const int base = m * 6144 + h * 64 + i;
    float qlo = bf2f(qkv[base]), qhi = bf2f(qkv[base + 32]);
    float klo = bf2f(qkv[base + 2048]), khi = bf2f(qkv[base + 2048 + 32]);
    const int ob = (bh * 2048 + l0 + l) * 64 + i;
    Q[ob] = f2bf((qlo * c - qhi * s) * QSC);
    Q[ob + 32] = f2bf((qhi * c + qlo * s) * QSC);
    Ko[ob] = f2bf(klo * c - khi * s);
    Ko[ob + 32] = f2bf(khi * c + klo * s);
  }

  __shared__ alignas(16) u16 vs[64][72];
#pragma unroll
  for (int it = 0; it < 2; ++it) {
    const int c = tid * 2 + it;
    const int l = c >> 3, off = (c & 7) * 8;
    const int m = b * 2048 + l0 + l;
    *(uint4*)&vs[l][off] = *(const uint4*)&qkv[m * 6144 + 4096 + h * 64 + off];
  }
  __syncthreads();
#pragma unroll
  for (int it = 0; it < 2; ++it) {
    const int c = tid * 2 + it;
    const int d = c >> 3, lc = (c & 7) * 8;
    u32 w0 = (u32)vs[lc + 0][d] | ((u32)vs[lc + 1][d] << 16);
    u32 w1 = (u32)vs[lc + 2][d] | ((u32)vs[lc + 3][d] << 16);
    u32 w2 = (u32)vs[lc + 4][d] | ((u32)vs[lc + 5][d] << 16);
    u32 w3 = (u32)vs[lc + 6][d] | ((u32)vs[lc + 7][d] << 16);
    uint4 pk; pk.x = w0; pk.y = w1; pk.z = w2; pk.w = w3;
    *(uint4*)&VT[(size_t)(bh * 64 + d) * 2048 + l0 + lc] = pk;
  }
}

// ---------------------------------------------------------------- flash attention (causal)
__global__ __launch_bounds__(256) void flash_kernel(const u16* __restrict__ Q,
                                                    const u16* __restrict__ K,
                                                    const u16* __restrict__ V,
                                                    u16* __restrict__ O) {
  __shared__ alignas(16) u16 KVs[2][2][64][64];
  __shared__ alignas(16) u16 Ps2[4][2][2][64][8];
  const int bid = blockIdx.x;
  const int xcd = bid & 7, slot = bid >> 3;
  const int bh = xcd * 8 + (slot & 7);
  const int pair = slot >> 3;
  const int b = bh >> 5, h = bh & 31;
  const int tid = threadIdx.x;
  const int w = tid >> 6, lane = tid & 63;
  const int g = lane >> 4, lo = lane & 15;
  const size_t bh2048 = (size_t)bh * 2048;
  const int srow = tid >> 3;
  const int sc8 = tid & 7;

  auto stage = [&](int buf, int kv0) {
#pragma unroll
    for (int p = 0; p < 2; ++p) {
      const int r = p * 32 + srow;
      const int col8 = sc8 ^ (r & 7);
      const u16* gk = K + (bh2048 + kv0 + r) * 64 + col8 * 8;
      const u16* gv = V + ((size_t)bh * 64 + r) * 2048 + kv0 + col8 * 8;
      u16* lbase = &KVs[buf][0][0][0] + p * 2048 + w * 512;
      GLDS16(gk, lbase);
      GLDS16(gv, lbase + 4096);
    }
  };

  for (int seg = 0; seg < 2; ++seg) {
    const int qt = seg ? 15 - pair : pair;
    const int qbase = qt * 128 + w * 32;
    const int ntile = 2 * qt + 2;
    const int nfree = 2 * qt;  // tiles < nfree need no causal mask for any wave

    bf16x8 qf[2][2];
#pragma unroll
    for (int qj = 0; qj < 2; ++qj)
#pragma unroll
      for (int ks = 0; ks < 2; ++ks)
        qf[qj][ks] = *(const bf16x8*)(Q + (bh2048 + qbase + qj * 16 + lo) * 64 + ks * 32 + g * 8);

    float mo[2] = {-1e30f, -1e30f};
    float ls[2] = {0.f, 0.f};
    f32x4 oacc[2][4] = {};

    stage(0, 0);
    __syncthreads();

    for (int t = 0; t < ntile; ++t) {
      const int cur = t & 1;
      const int kv0 = t * 64;
      if (t + 1 < ntile) stage(cur ^ 1, kv0 + 64);

      f32x4 st[4][2] = {};
#pragma unroll
      for (int kvi = 0; kvi < 4; ++kvi)
#pragma unroll
        for (int ks = 0; ks < 2; ++ks) {
          bf16x8 kf = *(const bf16x8*)&KVs[cur][0][kvi * 16 + lo][(ks * 32 + g * 8) ^ ((lo & 7) << 3)];
#pragma unroll
          for (int qj = 0; qj < 2; ++qj)
            st[kvi][qj] = __builtin_amdgcn_mfma_f32_16x16x32_bf16(kf, qf[qj][ks], st[kvi][qj], 0, 0, 0);
        }

      const bool need_mask = (t >= nfree);
      float corr2[2];
      int skipall = 1;
#pragma unroll
      for (int qj = 0; qj < 2; ++qj) {
        const int q = qbase + qj * 16 + lo;
        float tmax = -1e30f;
        if (need_mask) {
#pragma unroll
          for (int kvi = 0; kvi < 4; ++kvi)
#pragma unroll
            for (int r = 0; r < 4; ++r) {
              const int kv = kv0 + kvi * 16 + g * 4 + r;
              float s = st[kvi][qj][r];
              s = (kv <= q) ? s : -1e30f;
              st[kvi][qj][r] = s;
              tmax = fmaxf(tmax, s);
            }
        } else {
#pragma unroll
          for (int kvi = 0; kvi < 4; ++kvi)
#pragma unroll
            for (int r = 0; r < 4; ++r) tmax = fmaxf(tmax, st[kvi][qj][r]);
        }
        tmax = fmaxf(tmax, __shfl_xor(tmax, 16));
        tmax = fmaxf(tmax, __shfl_xor(tmax, 32));
        // defer-max (T13): skip rescale when max growth bounded (log2 units, 8 nats)
        const int sk = __all((int)(tmax <= mo[qj] + 11.54f));
        float mn;
        if (sk) {
          mn = mo[qj];
          corr2[qj] = 1.0f;
        } else {
          mn = fmaxf(mo[qj], tmax);
          corr2[qj] = exp2_fast(mo[qj] - mn);
          mo[qj] = mn;
          skipall = 0;
        }
        float psum = 0.f;
#pragma unroll
        for (int kvi = 0; kvi < 4; ++kvi) {
          float p0 = exp2_fast(st[kvi][qj][0] - mn);
          float p1 = exp2_fast(st[kvi][qj][1] - mn);
          float p2 = exp2_fast(st[kvi][qj][2] - mn);
          float p3 = exp2_fast(st[kvi][qj][3] - mn);
          psum += (p0 + p1) + (p2 + p3);
          bf16x4 pk;
          pk[0] = (__bf16)p0; pk[1] = (__bf16)p1; pk[2] = (__bf16)p2; pk[3] = (__bf16)p3;
          *(bf16x4*)&Ps2[w][qj][kvi >> 1][((kvi & 1) * 2 + (g >> 1)) * 16 + lo][(g & 1) * 4] = pk;
        }
        psum += __shfl_xor(psum, 16);
        psum += __shfl_xor(psum, 32);
        ls[qj] = ls[qj] * corr2[qj] + psum;
      }

      if (!skipall) {
#pragma unroll
        for (int qi = 0; qi < 2; ++qi)
#pragma unroll
          for (int r = 0; r < 4; ++r) {
            const float cc = __shfl(corr2[qi], g * 4 + r);
#pragma unroll
            for (int ni = 0; ni < 4; ++ni) oacc[qi][ni][r] *= cc;
          }
      }

      asm volatile("" ::: "memory");

      bf16x8 pa[2][2];
#pragma unroll
      for (int qi = 0; qi < 2; ++qi)
#pragma unroll
        for (int ks = 0; ks < 2; ++ks)
          pa[qi][ks] = *(const bf16x8*)&Ps2[w][qi][ks][lane][0];
#pragma unroll
      for (int ks = 0; ks < 2; ++ks)
#pragma unroll
        for (int ni = 0; ni < 4; ++ni) {
          bf16x8 vb = *(const bf16x8*)&KVs[cur][1][ni * 16 + lo][(ks * 32 + g * 8) ^ ((lo & 7) << 3)];
#pragma unroll
          for (int qi = 0; qi < 2; ++qi)
            oacc[qi][ni] = __builtin_amdgcn_mfma_f32_16x16x32_bf16(pa[qi][ks], vb, oacc[qi][ni], 0, 0, 0);
        }
      __syncthreads();
    }

#pragma unroll
    for (int qi = 0; qi < 2; ++qi) {
      const float linv = 1.0f / ls[qi];
#pragma unroll
      for (int r = 0; r < 4; ++r) {
        const float li = __shfl(linv, g * 4 + r);
        const int q = qbase + qi * 16 + g * 4 + r;
        const size_t rowoff = (size_t)(b * 2048 + q) * 2048 + h * 64;
#pragma unroll
        for (int ni = 0; ni < 4; ++ni)
          O[rowoff + ni * 16 + lo] = f2bf(oacc[qi][ni][r] * li);
      }
    }
  }
}

// ---------------------------------------------------------------- launch
extern "C" void kernel_launch(void* const* d_in, const int* in_sizes, int n_in,
                              void* d_out, int out_size, void* d_ws, size_t ws_size,
                              hipStream_t stream) {
  const float* x = (const float*)d_in[0];
  const float* wqkv = (const float*)d_in[1];
  const float* wo = (const float*)d_in[2];
  float* out = (float*)d_out;

  u16* xb = (u16*)d_ws;
  u16* wqkvb = xb + (size_t)8388608;
  u16* wob = wqkvb + (size_t)12582912;
  u16* qkv = wob + (size_t)4194304;
  u16* qr = qkv + (size_t)25165824;
  u16* kr = qr + (size_t)8388608;
  u16* vt = kr + (size_t)8388608;
  u16* aout = xb;

  hipFuncSetAttribute((const void*)gemm256<1, 4>, hipFuncAttributeMaxDynamicSharedMemorySize, 131072);
  hipFuncSetAttribute((const void*)gemm256<0, 2>, hipFuncAttributeMaxDynamicSharedMemorySize, 98304);

  cvt_kernel<<<1024, 256, 0, stream>>>(x, xb, 8388608 / 4);
  cvt_kernel<<<1024, 256, 0, stream>>>(wqkv, wqkvb, 12582912 / 4);
  cvt_kernel<<<512, 256, 0, stream>>>(wo, wob, 4194304 / 4);

  // qkv = x @ wqkv^T : M=4096, N=6144, K=2048 (256x256 tiles, 384 blocks)
  gemm256<1, 4><<<dim3(24, 16), 512, 131072, stream>>>(xb, wqkvb, qkv, 4096, 6144, 2048);

  // RoPE + split/transpose
  rope_kernel<<<dim3(64, 32), 256, 0, stream>>>(qkv, qr, kr, vt);

  // causal flash attention
  flash_kernel<<<dim3(512), 256, 0, stream>>>(qr, kr, vt, aout);

  // out = attn @ wo^T : M=4096, N=2048, K=2048 (256x128 tiles, 256 blocks = exact fill)
  gemm256<0, 2><<<dim3(16, 16), 512, 98304, stream>>>(aout, wob, out, 4096, 2048, 2048);
}